// Round 1
// baseline (248.910 us; speedup 1.0000x reference)
//
#include <hip/hip_runtime.h>
#include <cstdint>

// ---------------- problem constants ----------------
#define D_MODEL 1024
#define NHEADS  16
#define DKH     64
#define SEQ     2048
#define NBATCH  2
#define MROWS   (NBATCH*SEQ)   // 4096
#define RTYPES  8

typedef __bf16 bf16;
typedef __bf16 bf16x4v __attribute__((ext_vector_type(4)));
typedef __bf16 bf16x8v __attribute__((ext_vector_type(8)));
typedef float  f32x4v  __attribute__((ext_vector_type(4)));

typedef unsigned int __attribute__((address_space(1))) as1_u32;
typedef unsigned int __attribute__((address_space(3))) as3_u32;

static __device__ __forceinline__ void gload_lds16(const void* g, void* l) {
  __builtin_amdgcn_global_load_lds((const as1_u32*)(uintptr_t)g,
                                   (as3_u32*)(uintptr_t)l, 16, 0, 0);
}

static __device__ __forceinline__ f32x4v mfma16(bf16x8v a, bf16x8v b, f32x4v c) {
  return __builtin_amdgcn_mfma_f32_16x16x32_bf16(a, b, c, 0, 0, 0);
}

// ---------------- fp32 -> bf16 conversion (x + 4 weights) ----------------
__global__ void convert_kernel(const float* __restrict__ x,  const float* __restrict__ wq,
                               const float* __restrict__ wk, const float* __restrict__ wv,
                               const float* __restrict__ wo,
                               bf16* __restrict__ xb,  bf16* __restrict__ wqb,
                               bf16* __restrict__ wkb, bf16* __restrict__ wvb,
                               bf16* __restrict__ wob)
{
  int y = blockIdx.y;
  const float* src; bf16* dst; int cnt;
  if (y == 0)      { src = x;  dst = xb;  cnt = MROWS*D_MODEL/4; }
  else if (y == 1) { src = wq; dst = wqb; cnt = D_MODEL*D_MODEL/4; }
  else if (y == 2) { src = wk; dst = wkb; cnt = D_MODEL*D_MODEL/4; }
  else if (y == 3) { src = wv; dst = wvb; cnt = D_MODEL*D_MODEL/4; }
  else             { src = wo; dst = wob; cnt = D_MODEL*D_MODEL/4; }
  int i = blockIdx.x*256 + threadIdx.x;
  if (i >= cnt) return;
  float4 v = ((const float4*)src)[i];
  bf16x4v o = { (bf16)v.x, (bf16)v.y, (bf16)v.z, (bf16)v.w };
  ((bf16x4v*)dst)[i] = o;
}

// ---------------- NT GEMM: out[m][n] = sum_k A[m][k]*Bw[n][k] + bias[n] ----------------
// MODE 0: bf16 out -> [b][h][s][dk] with scale (Q: 0.125, K: 1.0)
// MODE 1: bf16 out -> [b][h][dk][s]  (V transposed)
// MODE 2: f32  out -> [m][n]         (final projection)
template<int MODE>
__global__ __launch_bounds__(256) void gemm_bt_kernel(
    const bf16* __restrict__ A, const bf16* __restrict__ Bw,
    const float* __restrict__ bias, void* __restrict__ outp, float scale)
{
  const int K  = D_MODEL;
  const int n0 = blockIdx.x*128, m0 = blockIdx.y*128;
  const int tid = threadIdx.x;
  const int w = tid>>6, lane = tid&63, g = lane>>4, c = lane&15;
  const int wm = w>>1, wn = w&1;

  __shared__ __align__(16) bf16 a_lds[128*32];
  __shared__ __align__(16) bf16 b_lds[128*32];

  const f32x4v fzero = {0.f,0.f,0.f,0.f};
  f32x4v acc[4][4];
  for (int i=0;i<4;i++) for (int j=0;j<4;j++) acc[i][j] = fzero;

  for (int k0=0;k0<K;k0+=32){
    __syncthreads();
    {
      int chunk = tid;                 // chunks 0..255
      int row = chunk>>2, c8 = chunk&3;
      gload_lds16(A  + (size_t)(m0+row)*K + k0 + c8*8, &a_lds[(w*64)*8]);
      gload_lds16(Bw + (size_t)(n0+row)*K + k0 + c8*8, &b_lds[(w*64)*8]);
      chunk = 256 + tid;               // chunks 256..511
      row = chunk>>2; c8 = chunk&3;
      gload_lds16(A  + (size_t)(m0+row)*K + k0 + c8*8, &a_lds[(256 + w*64)*8]);
      gload_lds16(Bw + (size_t)(n0+row)*K + k0 + c8*8, &b_lds[(256 + w*64)*8]);
    }
    asm volatile("s_waitcnt vmcnt(0)" ::: "memory");
    __syncthreads();

    bf16x8v af[4], bfv[4];
    #pragma unroll
    for (int mt=0;mt<4;mt++)
      af[mt] = *(const bf16x8v*)&a_lds[(wm*64 + mt*16 + c)*32 + g*8];
    #pragma unroll
    for (int nt=0;nt<4;nt++)
      bfv[nt] = *(const bf16x8v*)&b_lds[(wn*64 + nt*16 + c)*32 + g*8];
    #pragma unroll
    for (int mt=0;mt<4;mt++)
      #pragma unroll
      for (int nt=0;nt<4;nt++)
        acc[mt][nt] = mfma16(af[mt], bfv[nt], acc[mt][nt]);
  }

  #pragma unroll
  for (int mt=0;mt<4;mt++){
    #pragma unroll
    for (int nt=0;nt<4;nt++){
      #pragma unroll
      for (int r=0;r<4;r++){
        int m = m0 + wm*64 + mt*16 + g*4 + r;
        int n = n0 + wn*64 + nt*16 + c;
        float v = acc[mt][nt][r] + bias[n];
        if (MODE == 0){
          v *= scale;
          int bb=m>>11, s=m&2047, hh=n>>6, dk=n&63;
          ((bf16*)outp)[(((size_t)bb*NHEADS+hh)*SEQ + s)*DKH + dk] = (bf16)v;
        } else if (MODE == 1){
          int bb=m>>11, s=m&2047, hh=n>>6, dk=n&63;
          ((bf16*)outp)[(((size_t)bb*NHEADS+hh)*DKH + dk)*SEQ + s] = (bf16)v;
        } else {
          ((float*)outp)[(size_t)m*D_MODEL + n] = v;
        }
      }
    }
  }
}

// ---------------- flash attention with resource bias ----------------
// grid: (SEQ/64, NHEADS, NBATCH), 256 threads. Wave w owns 16 q-rows.
// Q pre-scaled by 1/sqrt(64). K: [b][h][s][dk]. V transposed: [b][h][dk][s].
__global__ __launch_bounds__(256) void attn_kernel(
    const bf16* __restrict__ Qg, const bf16* __restrict__ Kg,
    const bf16* __restrict__ Vtg, const float* __restrict__ rbias,
    const int* __restrict__ rmask, const int* __restrict__ amask,
    bf16* __restrict__ Og)
{
  const int b = blockIdx.z, h = blockIdx.y, q0 = blockIdx.x*64;
  const int tid = threadIdx.x;
  const int w = tid>>6, lane = tid&63, g = lane>>4, c = lane&15;
  const int bh = b*NHEADS + h;

  __shared__ __align__(16) bf16 k_lds[64][72];    // +8 pad: 2-way LDS conflicts only
  __shared__ __align__(16) bf16 vt_lds[64][72];
  __shared__ __align__(16) bf16 p_lds[4][16][72]; // wave-private P tiles
  __shared__ float rb_lds[RTYPES*RTYPES];
  __shared__ int   rj_lds[64];
  __shared__ float am_lds[64];

  if (tid < RTYPES*RTYPES) rb_lds[tid] = rbias[h*RTYPES*RTYPES + tid];

  const int qrow = q0 + w*16 + c;
  const bf16* qptr = Qg + ((size_t)bh*SEQ + qrow)*DKH;
  bf16x8v qf[2];
  qf[0] = *(const bf16x8v*)(qptr + g*8);
  qf[1] = *(const bf16x8v*)(qptr + 32 + g*8);

  int ri[4];
  #pragma unroll
  for (int r=0;r<4;r++) ri[r] = rmask[b*SEQ + q0 + w*16 + g*4 + r];

  const f32x4v fzero = {0.f,0.f,0.f,0.f};
  f32x4v oacc[4];
  #pragma unroll
  for (int dt=0;dt<4;dt++) oacc[dt] = fzero;
  float mrow[4] = {-1e30f,-1e30f,-1e30f,-1e30f};
  float lrow[4] = {0.f,0.f,0.f,0.f};

  for (int j0=0;j0<SEQ;j0+=64){
    __syncthreads();
    #pragma unroll
    for (int i=0;i<2;i++){
      int chunk = i*256 + tid;
      int row = chunk>>3, c8 = chunk&7;
      *(uint4*)&k_lds[row][c8*8]  = *(const uint4*)(Kg  + ((size_t)bh*SEQ + j0 + row)*DKH + c8*8);
      *(uint4*)&vt_lds[row][c8*8] = *(const uint4*)(Vtg + ((size_t)bh*DKH + row)*SEQ + j0 + c8*8);
    }
    if (tid < 64){
      rj_lds[tid] = rmask[b*SEQ + j0 + tid];
      am_lds[tid] = amask[b*SEQ + j0 + tid] ? 0.f : -1e9f;
    }
    __syncthreads();

    // S = Q K^T  (already includes 1/sqrt(dk) via Q)
    f32x4v s[4];
    #pragma unroll
    for (int nt=0;nt<4;nt++){
      f32x4v z = fzero;
      #pragma unroll
      for (int kt=0;kt<2;kt++){
        bf16x8v kf = *(const bf16x8v*)&k_lds[nt*16 + c][kt*32 + g*8];
        z = mfma16(qf[kt], kf, z);
      }
      s[nt] = z;
    }

    // + resource bias + attention mask
    #pragma unroll
    for (int nt=0;nt<4;nt++){
      int jc = nt*16 + c;
      float am = am_lds[jc];
      int rj = rj_lds[jc];
      #pragma unroll
      for (int r=0;r<4;r++)
        s[nt][r] += rb_lds[ri[r]*RTYPES + rj] + am;
    }

    // online softmax (rows live in 16-lane groups; reduce over lane&15)
    float scl[4], psum[4];
    #pragma unroll
    for (int r=0;r<4;r++){
      float mx = fmaxf(fmaxf(s[0][r], s[1][r]), fmaxf(s[2][r], s[3][r]));
      mx = fmaxf(mx, __shfl_xor(mx, 1));
      mx = fmaxf(mx, __shfl_xor(mx, 2));
      mx = fmaxf(mx, __shfl_xor(mx, 4));
      mx = fmaxf(mx, __shfl_xor(mx, 8));
      float mnew = fmaxf(mrow[r], mx);
      scl[r] = exp2f((mrow[r] - mnew) * 1.44269504f);
      mrow[r] = mnew;
      float sum = 0.f;
      #pragma unroll
      for (int nt=0;nt<4;nt++){
        float p = exp2f((s[nt][r] - mnew) * 1.44269504f);
        s[nt][r] = p;
        sum += p;
      }
      sum += __shfl_xor(sum, 1);
      sum += __shfl_xor(sum, 2);
      sum += __shfl_xor(sum, 4);
      sum += __shfl_xor(sum, 8);
      psum[r] = sum;
      lrow[r] = lrow[r]*scl[r] + psum[r];
    }

    // P -> bf16 -> wave-private LDS (D-layout -> A-layout transpose)
    #pragma unroll
    for (int nt=0;nt<4;nt++)
      #pragma unroll
      for (int r=0;r<4;r++)
        p_lds[w][g*4+r][nt*16+c] = (bf16)s[nt][r];

    // O = O*scl + P V   (V^T rows are d, contiguous in j)
    #pragma unroll
    for (int dt=0;dt<4;dt++){
      f32x4v a = oacc[dt];
      #pragma unroll
      for (int r=0;r<4;r++) a[r] *= scl[r];
      #pragma unroll
      for (int kt=0;kt<2;kt++){
        bf16x8v pf = *(const bf16x8v*)&p_lds[w][c][kt*32 + g*8];
        bf16x8v vf = *(const bf16x8v*)&vt_lds[dt*16 + c][kt*32 + g*8];
        a = mfma16(pf, vf, a);
      }
      oacc[dt] = a;
    }
  }

  // normalize + store merged-head layout [b][s][h*64+d] as bf16
  #pragma unroll
  for (int dt=0;dt<4;dt++){
    #pragma unroll
    for (int r=0;r<4;r++){
      float o = oacc[dt][r] / lrow[r];
      int row = q0 + w*16 + g*4 + r;
      int col = h*DKH + dt*16 + c;
      Og[(size_t)(b*SEQ + row)*D_MODEL + col] = (bf16)o;
    }
  }
}

// ---------------- launch ----------------
extern "C" void kernel_launch(void* const* d_in, const int* in_sizes, int n_in,
                              void* d_out, int out_size, void* d_ws, size_t ws_size,
                              hipStream_t stream)
{
  (void)in_sizes; (void)n_in; (void)out_size; (void)ws_size;
  const float* x     = (const float*)d_in[0];
  const float* Wq    = (const float*)d_in[1];
  const float* bq    = (const float*)d_in[2];
  const float* Wk    = (const float*)d_in[3];
  const float* bk    = (const float*)d_in[4];
  const float* Wv    = (const float*)d_in[5];
  const float* bv    = (const float*)d_in[6];
  const float* Wo    = (const float*)d_in[7];
  const float* bo    = (const float*)d_in[8];
  const float* rbias = (const float*)d_in[9];
  const int*   rmask = (const int*)d_in[10];
  const int*   amask = (const int*)d_in[11];
  float* out = (float*)d_out;

  char* ws = (char*)d_ws;
  bf16* xb  = (bf16*)(ws);                    //  8 MB  x bf16 [4096][1024]
  bf16* wqb = (bf16*)(ws + (8u<<20));         //  2 MB each
  bf16* wkb = (bf16*)(ws + (10u<<20));
  bf16* wvb = (bf16*)(ws + (12u<<20));
  bf16* wob = (bf16*)(ws + (14u<<20));
  bf16* qb  = (bf16*)(ws + (16u<<20));        //  8 MB  Q [b][h][s][dk] (pre-scaled)
  bf16* kb  = (bf16*)(ws + (24u<<20));        //  8 MB  K [b][h][s][dk]
  bf16* vtb = (bf16*)(ws + (32u<<20));        //  8 MB  V^T [b][h][dk][s]
  bf16* aob = (bf16*)(ws + (40u<<20));        //  8 MB  attn out [s][e]

  convert_kernel<<<dim3(4096,5), 256, 0, stream>>>(x,Wq,Wk,Wv,Wo, xb,wqb,wkb,wvb,wob);

  dim3 ggrid(D_MODEL/128, MROWS/128);
  gemm_bt_kernel<0><<<ggrid, 256, 0, stream>>>(xb, wqb, bq, qb, 0.125f);
  gemm_bt_kernel<0><<<ggrid, 256, 0, stream>>>(xb, wkb, bk, kb, 1.0f);
  gemm_bt_kernel<1><<<ggrid, 256, 0, stream>>>(xb, wvb, bv, vtb, 1.0f);

  attn_kernel<<<dim3(SEQ/64, NHEADS, NBATCH), 256, 0, stream>>>(qb, kb, vtb, rbias, rmask, amask, aob);

  gemm_bt_kernel<2><<<ggrid, 256, 0, stream>>>(aob, wob, bo, out, 1.0f);
}

// Round 2
// 207.369 us; speedup vs baseline: 1.2003x; 1.2003x over previous
//
#include <hip/hip_runtime.h>
#include <cstdint>

// ---------------- problem constants ----------------
#define D_MODEL 1024
#define NHEADS  16
#define DKH     64
#define SEQ     2048
#define NBATCH  2
#define MROWS   (NBATCH*SEQ)   // 4096
#define RTYPES  8
#define LOG2E   1.44269504f

typedef __bf16 bf16;
typedef __bf16 bf16x4v __attribute__((ext_vector_type(4)));
typedef __bf16 bf16x8v __attribute__((ext_vector_type(8)));
typedef float  f32x4v  __attribute__((ext_vector_type(4)));

typedef unsigned int __attribute__((address_space(1))) as1_u32;
typedef unsigned int __attribute__((address_space(3))) as3_u32;

static __device__ __forceinline__ void gload_lds16(const void* g, void* l) {
  __builtin_amdgcn_global_load_lds((const as1_u32*)(uintptr_t)g,
                                   (as3_u32*)(uintptr_t)l, 16, 0, 0);
}

static __device__ __forceinline__ f32x4v mfma16(bf16x8v a, bf16x8v b, f32x4v c) {
  return __builtin_amdgcn_mfma_f32_16x16x32_bf16(a, b, c, 0, 0, 0);
}

// ---------------- fp32 -> bf16 conversion (x + 4 weights) ----------------
__global__ void convert_kernel(const float* __restrict__ x,  const float* __restrict__ wq,
                               const float* __restrict__ wk, const float* __restrict__ wv,
                               const float* __restrict__ wo,
                               bf16* __restrict__ xb,  bf16* __restrict__ wqb,
                               bf16* __restrict__ wkb, bf16* __restrict__ wvb,
                               bf16* __restrict__ wob)
{
  int y = blockIdx.y;
  const float* src; bf16* dst; int cnt;
  if (y == 0)      { src = x;  dst = xb;  cnt = MROWS*D_MODEL/4; }
  else if (y == 1) { src = wq; dst = wqb; cnt = D_MODEL*D_MODEL/4; }
  else if (y == 2) { src = wk; dst = wkb; cnt = D_MODEL*D_MODEL/4; }
  else if (y == 3) { src = wv; dst = wvb; cnt = D_MODEL*D_MODEL/4; }
  else             { src = wo; dst = wob; cnt = D_MODEL*D_MODEL/4; }
  int i = blockIdx.x*256 + threadIdx.x;
  if (i >= cnt) return;
  float4 v = ((const float4*)src)[i];
  bf16x4v o = { (bf16)v.x, (bf16)v.y, (bf16)v.z, (bf16)v.w };
  ((bf16x4v*)dst)[i] = o;
}

// ---------------- bias precompute: biasg[b][h][t][j] = (rb[h][t][rj[b][j]] + am(b,j))*LOG2E
__global__ void bias_precompute_kernel(const float* __restrict__ rbias,
                                       const int* __restrict__ rmask,
                                       const int* __restrict__ amask,
                                       float* __restrict__ biasg)
{
  int idx = blockIdx.x*512 + threadIdx.x;          // 2*16*8*2048 = 524288
  int j  = idx & (SEQ-1);
  int t  = (idx >> 11) & 7;
  int hh = (idx >> 14) & 15;
  int bb = idx >> 18;
  int rj = rmask[bb*SEQ + j];
  float am = amask[bb*SEQ + j] ? 0.f : -1e9f;
  biasg[idx] = (rbias[(hh*RTYPES + t)*RTYPES + rj] + am) * LOG2E;
}

// ---------------- NT GEMM: out[m][n] = (sum_k A[m][k]*Bw[n][k] + bias[n]) * scale ----
// MODE 0: bf16 out -> [b][h][s][dk]  (Q: scale=0.125*LOG2E, K: 1.0)
// MODE 1: bf16 out -> [b][h][dk][s]  (V transposed)
// MODE 2: f32  out -> [m][n]         (final projection)
template<int MODE>
__global__ __launch_bounds__(256) void gemm_bt_kernel(
    const bf16* __restrict__ A, const bf16* __restrict__ Bw,
    const float* __restrict__ bias, void* __restrict__ outp, float scale)
{
  const int K  = D_MODEL;
  const int n0 = blockIdx.x*128, m0 = blockIdx.y*128;
  const int tid = threadIdx.x;
  const int w = tid>>6, lane = tid&63, g = lane>>4, c = lane&15;
  const int wm = w>>1, wn = w&1;

  __shared__ __align__(16) bf16 a_lds[128*32];
  __shared__ __align__(16) bf16 b_lds[128*32];

  const f32x4v fzero = {0.f,0.f,0.f,0.f};
  f32x4v acc[4][4];
  for (int i=0;i<4;i++) for (int j=0;j<4;j++) acc[i][j] = fzero;

  for (int k0=0;k0<K;k0+=32){
    __syncthreads();
    {
      int chunk = tid;
      int row = chunk>>2, c8 = chunk&3;
      gload_lds16(A  + (size_t)(m0+row)*K + k0 + c8*8, &a_lds[(w*64)*8]);
      gload_lds16(Bw + (size_t)(n0+row)*K + k0 + c8*8, &b_lds[(w*64)*8]);
      chunk = 256 + tid;
      row = chunk>>2; c8 = chunk&3;
      gload_lds16(A  + (size_t)(m0+row)*K + k0 + c8*8, &a_lds[(256 + w*64)*8]);
      gload_lds16(Bw + (size_t)(n0+row)*K + k0 + c8*8, &b_lds[(256 + w*64)*8]);
    }
    asm volatile("s_waitcnt vmcnt(0)" ::: "memory");
    __syncthreads();

    bf16x8v af[4], bfv[4];
    #pragma unroll
    for (int mt=0;mt<4;mt++)
      af[mt] = *(const bf16x8v*)&a_lds[(wm*64 + mt*16 + c)*32 + g*8];
    #pragma unroll
    for (int nt=0;nt<4;nt++)
      bfv[nt] = *(const bf16x8v*)&b_lds[(wn*64 + nt*16 + c)*32 + g*8];
    #pragma unroll
    for (int mt=0;mt<4;mt++)
      #pragma unroll
      for (int nt=0;nt<4;nt++)
        acc[mt][nt] = mfma16(af[mt], bfv[nt], acc[mt][nt]);
  }

  #pragma unroll
  for (int mt=0;mt<4;mt++){
    #pragma unroll
    for (int nt=0;nt<4;nt++){
      #pragma unroll
      for (int r=0;r<4;r++){
        int m = m0 + wm*64 + mt*16 + g*4 + r;
        int n = n0 + wn*64 + nt*16 + c;
        float v = acc[mt][nt][r] + bias[n];
        if (MODE == 0){
          v *= scale;
          int bb=m>>11, s=m&2047, hh=n>>6, dk=n&63;
          ((bf16*)outp)[(((size_t)bb*NHEADS+hh)*SEQ + s)*DKH + dk] = (bf16)v;
        } else if (MODE == 1){
          int bb=m>>11, s=m&2047, hh=n>>6, dk=n&63;
          ((bf16*)outp)[(((size_t)bb*NHEADS+hh)*DKH + dk)*SEQ + s] = (bf16)v;
        } else {
          ((float*)outp)[(size_t)m*D_MODEL + n] = v;
        }
      }
    }
  }
}

// ---------------- flash attention v2 ----------------
// grid (SEQ/128, NHEADS, NBATCH), 512 threads (8 waves x 16 q-rows).
// Q pre-scaled by 0.125*LOG2E (exp2-domain softmax). K tile j-permuted so MFMA
// tile nt, col c <-> logical j = 4c+nt (bias read = 1x b128, P write = 1x b64).
// K/Vt/P LDS tiles XOR-swizzled byte^=(row&7)<<4; staging via global_load_lds
// with pre-swizzled per-lane SOURCE address (linear LDS dest). Double-buffered
// 2-phase: issue stage(t+1) -> compute(t) -> __syncthreads (vmcnt0+barrier).
__global__ __launch_bounds__(512, 4) void attn_kernel(
    const bf16* __restrict__ Qg, const bf16* __restrict__ Kg,
    const bf16* __restrict__ Vtg, const float* __restrict__ biasg,
    bf16* __restrict__ Og)
{
  const int b = blockIdx.z, h = blockIdx.y, q0 = blockIdx.x*128;
  const int tid = threadIdx.x;
  const int w = tid>>6, lane = tid&63, g = lane>>4, c = lane&15;
  const int bh = b*NHEADS + h;

  __shared__ __align__(16) bf16 k_lds[2][64*64];   // 16 KB, row=128B, swizzled
  __shared__ __align__(16) bf16 vt_lds[2][64*64];  // 16 KB
  __shared__ __align__(16) bf16 p_lds[8][16*64];   // 16 KB (wave-private 2KB)
  __shared__ __align__(16) float bias_lds[2][8*64];// 4 KB

  // Q fragment (A-operand): row=c, k-slice g*8
  const int qrow = q0 + w*16 + c;
  const bf16* qptr = Qg + ((size_t)bh*SEQ + qrow)*DKH;
  bf16x8v qf[2];
  qf[0] = *(const bf16x8v*)(qptr + g*8);
  qf[1] = *(const bf16x8v*)(qptr + 32 + g*8);

  const f32x4v fzero = {0.f,0.f,0.f,0.f};
  f32x4v oacc[4];
  #pragma unroll
  for (int dt=0;dt<4;dt++) oacc[dt] = fzero;
  float mrow[4] = {-1e30f,-1e30f,-1e30f,-1e30f};
  float lrow[4] = {0.f,0.f,0.f,0.f};

  // per-lane resource class of the 4 owned q-rows -> bias row select
  int ri[4];
  #pragma unroll
  for (int r=0;r<4;r++) ri[r] = ((const int*)nullptr == nullptr) ? 0 : 0; // placeholder, set below
  // (real init below; biasg already folds rj+am; we only need ri rows)
  // ri[r] indexes bias_lds rows: bias_lds[t][j'] with t = resource type of the Q row.
  // We don't have rmask here anymore -> pass via biasg? No: ri is the Q-side type.
  // Load it directly from global rmask is not passed; instead biasg is indexed by t,
  // so we must know t = rmask[b][qrow_r]. We pass rmask via Qg? -- see launch: we
  // kept rmask in biasg's tail. (Actually: rmask pointer is passed separately below.)
  (void)ri;

  // --- the above placeholder is unused; real kernel body continues in attn_kernel2 ---
  (void)k_lds; (void)vt_lds; (void)p_lds; (void)bias_lds; (void)Og; (void)qf; (void)oacc;
  (void)mrow; (void)lrow; (void)w; (void)lane; (void)g; (void)c; (void)q0;
}

// Real attention kernel (rmask needed for Q-side resource class).
__global__ __launch_bounds__(512, 4) void attn2_kernel(
    const bf16* __restrict__ Qg, const bf16* __restrict__ Kg,
    const bf16* __restrict__ Vtg, const float* __restrict__ biasg,
    const int* __restrict__ rmask, bf16* __restrict__ Og)
{
  const int b = blockIdx.z, h = blockIdx.y, q0 = blockIdx.x*128;
  const int tid = threadIdx.x;
  const int w = tid>>6, lane = tid&63, g = lane>>4, c = lane&15;
  const int bh = b*NHEADS + h;

  __shared__ __align__(16) bf16 k_lds[2][64*64];
  __shared__ __align__(16) bf16 vt_lds[2][64*64];
  __shared__ __align__(16) bf16 p_lds[8][16*64];
  __shared__ __align__(16) float bias_lds[2][8*64];

  const int qrow = q0 + w*16 + c;
  const bf16* qptr = Qg + ((size_t)bh*SEQ + qrow)*DKH;
  bf16x8v qf[2];
  qf[0] = *(const bf16x8v*)(qptr + g*8);
  qf[1] = *(const bf16x8v*)(qptr + 32 + g*8);

  int ri[4];
  #pragma unroll
  for (int r=0;r<4;r++) ri[r] = rmask[b*SEQ + q0 + w*16 + g*4 + r];

  const f32x4v fzero = {0.f,0.f,0.f,0.f};
  f32x4v oacc[4];
  #pragma unroll
  for (int dt=0;dt<4;dt++) oacc[dt] = fzero;
  float mrow[4] = {-1e30f,-1e30f,-1e30f,-1e30f};
  float lrow[4] = {0.f,0.f,0.f,0.f};

  // staging constants (per thread): 16B chunk ids
  const int rho = tid>>3;                       // 0..63: physical LDS row
  const int c8s = (tid&7) ^ ((tid>>3)&7);       // pre-swizzled source slot
  const int jsrcK = ((rho&15)<<2) + (rho>>4);   // K j-permutation: phys row -> logical j

  auto STAGE = [&](int j0, int nb){
    // K: LDS phys row rho holds logical j = (rho&15)*4 + (rho>>4), slots XOR (rho&7)
    gload_lds16(Kg  + ((size_t)bh*SEQ + j0 + jsrcK)*DKH + (c8s<<3), &k_lds[nb][w*512]);
    // Vt: LDS row rho = d (linear), slots XOR (rho&7)
    gload_lds16(Vtg + ((size_t)bh*DKH + rho)*SEQ + j0 + (c8s<<3),   &vt_lds[nb][w*512]);
    // bias tile: 8 rows x 64 floats, linear
    if (w < 2){
      int chunk = w*64 + lane;                  // 0..127
      int tcls = chunk>>4, c16 = chunk&15;
      gload_lds16(biasg + ((size_t)(bh*8 + tcls))*SEQ + j0 + c16*4, &bias_lds[nb][w*256]);
    }
  };

  auto COMPUTE = [&](int nb){
    const char* kb_ = (const char*)k_lds[nb];
    const char* vb_ = (const char*)vt_lds[nb];
    char* pw = (char*)p_lds[w];

    // S = Q K^T (exp2 domain); tile nt col c = logical j = 4c+nt
    f32x4v s[4];
    #pragma unroll
    for (int nt=0;nt<4;nt++){
      f32x4v z = fzero;
      #pragma unroll
      for (int kt=0;kt<2;kt++){
        const int row = nt*16 + c;
        bf16x8v kf = *(const bf16x8v*)(kb_ + row*128 + ((kt*64 + g*16) ^ ((row&7)<<4)));
        z = mfma16(qf[kt], kf, z);
      }
      s[nt] = z;
    }

    // + bias (rj + amask folded, *LOG2E): one b128 per row r covers j=4c..4c+3
    #pragma unroll
    for (int r=0;r<4;r++){
      f32x4v bv = *(const f32x4v*)&bias_lds[nb][ri[r]*64 + 4*c];
      #pragma unroll
      for (int nt=0;nt<4;nt++) s[nt][r] += bv[nt];
    }

    // online softmax per q-row (16-lane group reduce) + P write (b64)
    float scl[4];
    #pragma unroll
    for (int r=0;r<4;r++){
      float mx = fmaxf(fmaxf(s[0][r],s[1][r]), fmaxf(s[2][r],s[3][r]));
      mx = fmaxf(mx, __shfl_xor(mx,1));
      mx = fmaxf(mx, __shfl_xor(mx,2));
      mx = fmaxf(mx, __shfl_xor(mx,4));
      mx = fmaxf(mx, __shfl_xor(mx,8));
      float mnew = fmaxf(mrow[r], mx);
      scl[r] = exp2f(mrow[r] - mnew);
      mrow[r] = mnew;
      float sum = 0.f;
      #pragma unroll
      for (int nt=0;nt<4;nt++){ float p = exp2f(s[nt][r]-mnew); s[nt][r]=p; sum += p; }
      sum += __shfl_xor(sum,1);
      sum += __shfl_xor(sum,2);
      sum += __shfl_xor(sum,4);
      sum += __shfl_xor(sum,8);
      lrow[r] = lrow[r]*scl[r] + sum;

      bf16x4v pk = { (bf16)s[0][r], (bf16)s[1][r], (bf16)s[2][r], (bf16)s[3][r] };
      const int prow = g*4 + r;
      *(bf16x4v*)(pw + prow*128 + ((c*8) ^ ((prow&7)<<4))) = pk;
    }

    // O = O*scl + P V
    #pragma unroll
    for (int dt=0;dt<4;dt++){
      f32x4v a = oacc[dt];
      #pragma unroll
      for (int r=0;r<4;r++) a[r] *= scl[r];
      #pragma unroll
      for (int kt=0;kt<2;kt++){
        bf16x8v pf = *(const bf16x8v*)(pw + c*128 + ((kt*64 + g*16) ^ ((c&7)<<4)));
        const int vr = dt*16 + c;
        bf16x8v vf = *(const bf16x8v*)(vb_ + vr*128 + ((kt*64 + g*16) ^ ((vr&7)<<4)));
        a = mfma16(pf, vf, a);
      }
      oacc[dt] = a;
    }
  };

  STAGE(0, 0);
  __syncthreads();
  int cur = 0;
  for (int t=0; t<SEQ/64; ++t){
    if (t+1 < SEQ/64) STAGE((t+1)*64, cur^1);
    COMPUTE(cur);
    __syncthreads();
    cur ^= 1;
  }

  // normalize + store merged-head layout [b][s][h*64+d]
  #pragma unroll
  for (int dt=0;dt<4;dt++){
    #pragma unroll
    for (int r=0;r<4;r++){
      float o = oacc[dt][r] / lrow[r];
      int row = q0 + w*16 + g*4 + r;
      int col = h*DKH + dt*16 + c;
      Og[(size_t)(b*SEQ + row)*D_MODEL + col] = (bf16)o;
    }
  }
}

// ---------------- launch ----------------
extern "C" void kernel_launch(void* const* d_in, const int* in_sizes, int n_in,
                              void* d_out, int out_size, void* d_ws, size_t ws_size,
                              hipStream_t stream)
{
  (void)in_sizes; (void)n_in; (void)out_size; (void)ws_size;
  const float* x     = (const float*)d_in[0];
  const float* Wq    = (const float*)d_in[1];
  const float* bq    = (const float*)d_in[2];
  const float* Wk    = (const float*)d_in[3];
  const float* bk    = (const float*)d_in[4];
  const float* Wv    = (const float*)d_in[5];
  const float* bv    = (const float*)d_in[6];
  const float* Wo    = (const float*)d_in[7];
  const float* bo    = (const float*)d_in[8];
  const float* rbias = (const float*)d_in[9];
  const int*   rmask = (const int*)d_in[10];
  const int*   amask = (const int*)d_in[11];
  float* out = (float*)d_out;

  char* ws = (char*)d_ws;
  bf16*  xb    = (bf16*)(ws);                 //  8 MB
  bf16*  wqb   = (bf16*)(ws + (8u<<20));      //  2 MB each
  bf16*  wkb   = (bf16*)(ws + (10u<<20));
  bf16*  wvb   = (bf16*)(ws + (12u<<20));
  bf16*  wob   = (bf16*)(ws + (14u<<20));
  bf16*  qb    = (bf16*)(ws + (16u<<20));     //  8 MB Q [b][h][s][dk] (pre-scaled, exp2 domain)
  bf16*  kb    = (bf16*)(ws + (24u<<20));     //  8 MB K [b][h][s][dk]
  bf16*  vtb   = (bf16*)(ws + (32u<<20));     //  8 MB V^T [b][h][dk][s]
  bf16*  aob   = (bf16*)(ws + (40u<<20));     //  8 MB attn out [s][e]
  float* biasg = (float*)(ws + (48u<<20));    //  2 MB bias [b][h][8][S]

  convert_kernel<<<dim3(4096,5), 256, 0, stream>>>(x,Wq,Wk,Wv,Wo, xb,wqb,wkb,wvb,wob);
  bias_precompute_kernel<<<1024, 512, 0, stream>>>(rbias, rmask, amask, biasg);

  dim3 ggrid(D_MODEL/128, MROWS/128);
  gemm_bt_kernel<0><<<ggrid, 256, 0, stream>>>(xb, wqb, bq, qb, 0.125f*LOG2E);
  gemm_bt_kernel<0><<<ggrid, 256, 0, stream>>>(xb, wkb, bk, kb, 1.0f);
  gemm_bt_kernel<1><<<ggrid, 256, 0, stream>>>(xb, wvb, bv, vtb, 1.0f);

  attn2_kernel<<<dim3(SEQ/128, NHEADS, NBATCH), 512, 0, stream>>>(qb, kb, vtb, biasg, rmask, aob);

  gemm_bt_kernel<2><<<ggrid, 256, 0, stream>>>(aob, wob, bo, out, 1.0f);
}

// Round 4
// 142.256 us; speedup vs baseline: 1.7497x; 1.4577x over previous
//
#include <hip/hip_runtime.h>
#include <cstdint>

// ---------------- problem constants ----------------
#define D_MODEL 1024
#define NHEADS  16
#define DKH     64
#define SEQ     2048
#define NBATCH  2
#define MROWS   (NBATCH*SEQ)   // 4096
#define RTYPES  8
#define LOG2E   1.44269504f

typedef __bf16 bf16;
typedef __bf16 bf16x4v __attribute__((ext_vector_type(4)));
typedef __bf16 bf16x8v __attribute__((ext_vector_type(8)));
typedef float  f32x4v  __attribute__((ext_vector_type(4)));

typedef unsigned int __attribute__((address_space(1))) as1_u32;
typedef unsigned int __attribute__((address_space(3))) as3_u32;

static __device__ __forceinline__ void gload_lds16(const void* g, void* l) {
  __builtin_amdgcn_global_load_lds((const as1_u32*)(uintptr_t)g,
                                   (as3_u32*)(uintptr_t)l, 16, 0, 0);
}

static __device__ __forceinline__ f32x4v mfma16(bf16x8v a, bf16x8v b, f32x4v c) {
  return __builtin_amdgcn_mfma_f32_16x16x32_bf16(a, b, c, 0, 0, 0);
}

// ---------------- fp32->bf16 conversion + bias precompute (fused) ----------------
// grid (4096, 6) x 256. y=0: x (1048576 float4), y=1..4: weights (262144 each),
// y=5: bias table. biasg[b][h][t][j] = (rbias[h][t][rmask[b][j]] + (amask?0:-1e9))*LOG2E
__global__ void convert_kernel(const float* __restrict__ x,  const float* __restrict__ wq,
                               const float* __restrict__ wk, const float* __restrict__ wv,
                               const float* __restrict__ wo,
                               bf16* __restrict__ xb,  bf16* __restrict__ wqb,
                               bf16* __restrict__ wkb, bf16* __restrict__ wvb,
                               bf16* __restrict__ wob,
                               const float* __restrict__ rbias,
                               const int* __restrict__ rmask,
                               const int* __restrict__ amask,
                               float* __restrict__ biasg)
{
  int y = blockIdx.y;
  int i = blockIdx.x*256 + threadIdx.x;
  if (y == 0){
    // x: MROWS*D_MODEL/4 = 1048576 chunks, grid.x covers exactly
    float4 v = ((const float4*)x)[i];
    bf16x4v o = { (bf16)v.x, (bf16)v.y, (bf16)v.z, (bf16)v.w };
    ((bf16x4v*)xb)[i] = o;
  } else if (y < 5){
    if (i >= D_MODEL*D_MODEL/4) return;     // 262144 chunks per weight
    const float* src; bf16* dst;
    if (y == 1)      { src = wq; dst = wqb; }
    else if (y == 2) { src = wk; dst = wkb; }
    else if (y == 3) { src = wv; dst = wvb; }
    else             { src = wo; dst = wob; }
    float4 v = ((const float4*)src)[i];
    bf16x4v o = { (bf16)v.x, (bf16)v.y, (bf16)v.z, (bf16)v.w };
    ((bf16x4v*)dst)[i] = o;
  } else {
    if (i >= NHEADS*RTYPES*SEQ) return;     // 262144 entries per batch
    #pragma unroll
    for (int bb=0; bb<NBATCH; bb++){
      int idx = bb*(NHEADS*RTYPES*SEQ) + i;
      int j  = idx & (SEQ-1);
      int t  = (idx >> 11) & 7;
      int hh = (idx >> 14) & 15;
      int rj = rmask[bb*SEQ + j];
      float am = amask[bb*SEQ + j] ? 0.f : -1e9f;
      biasg[idx] = (rbias[(hh*RTYPES + t)*RTYPES + rj] + am) * LOG2E;
    }
  }
}

// ---------------- NT GEMM, 2-phase double-buffered ----------------
// FUSED=1: grid (8,32,3); z=0 -> Q [b][h][s][dk] (scale), z=1 -> K same, z=2 -> V^T [b][h][dk][s]
// FUSED=0: grid (8,32); f32 out [m][n]
struct GemmOuts { const bf16* W[3]; const float* bia[3]; void* out[3]; };

template<int FUSED>
__global__ __launch_bounds__(256, 3) void gemm_bt_kernel(
    const bf16* __restrict__ A, GemmOuts args, float qscale)
{
  const int K  = D_MODEL;
  const int z  = FUSED ? blockIdx.z : 0;
  const bf16*  Bw   = args.W[z];
  const float* bias = args.bia[z];
  void* outp        = args.out[z];
  const float scale = (FUSED && z==0) ? qscale : 1.0f;

  const int n0 = blockIdx.x*128, m0 = blockIdx.y*128;
  const int tid = threadIdx.x;
  const int w = tid>>6, lane = tid&63, g = lane>>4, c = lane&15;
  const int wm = w>>1, wn = w&1;

  __shared__ __align__(16) bf16 a_lds[2][128*32];
  __shared__ __align__(16) bf16 b_lds[2][128*32];

  const f32x4v fzero = {0.f,0.f,0.f,0.f};
  f32x4v acc[4][4];
  for (int i=0;i<4;i++) for (int j=0;j<4;j++) acc[i][j] = fzero;

  const int srow = tid>>2, sc8 = tid&3;

  auto STAGE = [&](int k0, int nb){
    gload_lds16(A  + (size_t)(m0+srow)*K     + k0 + sc8*8, &a_lds[nb][(w*64)*8]);
    gload_lds16(Bw + (size_t)(n0+srow)*K     + k0 + sc8*8, &b_lds[nb][(w*64)*8]);
    gload_lds16(A  + (size_t)(m0+64+srow)*K  + k0 + sc8*8, &a_lds[nb][(256 + w*64)*8]);
    gload_lds16(Bw + (size_t)(n0+64+srow)*K  + k0 + sc8*8, &b_lds[nb][(256 + w*64)*8]);
  };

  auto COMPUTE = [&](int nb){
    bf16x8v af[4], bfv[4];
    #pragma unroll
    for (int mt=0;mt<4;mt++)
      af[mt] = *(const bf16x8v*)&a_lds[nb][(wm*64 + mt*16 + c)*32 + g*8];
    #pragma unroll
    for (int nt=0;nt<4;nt++)
      bfv[nt] = *(const bf16x8v*)&b_lds[nb][(wn*64 + nt*16 + c)*32 + g*8];
    #pragma unroll
    for (int mt=0;mt<4;mt++)
      #pragma unroll
      for (int nt=0;nt<4;nt++)
        acc[mt][nt] = mfma16(af[mt], bfv[nt], acc[mt][nt]);
  };

  STAGE(0, 0);
  __syncthreads();
  int cur = 0;
  for (int k0=32; k0<K; k0+=32){
    STAGE(k0, cur^1);
    COMPUTE(cur);
    __syncthreads();
    cur ^= 1;
  }
  COMPUTE(cur);

  #pragma unroll
  for (int mt=0;mt<4;mt++){
    #pragma unroll
    for (int nt=0;nt<4;nt++){
      if (FUSED && z == 2){
        // V^T store: 4 consecutive s -> b64 vector store
        int m = m0 + wm*64 + mt*16 + g*4;
        int n = n0 + wn*64 + nt*16 + c;
        int bb=m>>11, s=m&2047, hh=n>>6, dk=n&63;
        float bn = bias[n];
        bf16x4v ov;
        #pragma unroll
        for (int r=0;r<4;r++) ov[r] = (bf16)(acc[mt][nt][r] + bn);
        *(bf16x4v*)&((bf16*)outp)[(((size_t)bb*NHEADS+hh)*DKH + dk)*SEQ + s] = ov;
      } else {
        #pragma unroll
        for (int r=0;r<4;r++){
          int m = m0 + wm*64 + mt*16 + g*4 + r;
          int n = n0 + wn*64 + nt*16 + c;
          float v = acc[mt][nt][r] + bias[n];
          if (FUSED){
            v *= scale;
            int bb=m>>11, s=m&2047, hh=n>>6, dk=n&63;
            ((bf16*)outp)[(((size_t)bb*NHEADS+hh)*SEQ + s)*DKH + dk] = (bf16)v;
          } else {
            ((float*)outp)[(size_t)m*D_MODEL + n] = v;
          }
        }
      }
    }
  }
}

// ---------------- flash attention v3: swapped QK^T, in-register softmax ----------------
// grid (SEQ/128, NHEADS, NBATCH) x 512 (8 waves, 16 q-rows each).
// Q pre-scaled 0.125*LOG2E; bias table pre-scaled LOG2E (exp2-domain).
// Swapped QK^T: S^T = mfma(A=K, B=Q) -> lane (g,c) owns q-row c with 16 j-values in regs.
// K tile rows sigma-permuted so lane's j-set = {kt*32 + g*8 + 0..7} -> P feeds PV B-operand
// with ZERO cross-lane movement. PV: O^T = mfma(A=V^T, B=P) -> output q=c stays lane-local.
// phys row rho = nt*16+i4 holds logical j = (nt&1)*32 + (i4>>2)*8 + (nt>>1)*4 + (i4&3)
__global__ __launch_bounds__(512, 4) void attn3_kernel(
    const bf16* __restrict__ Qg, const bf16* __restrict__ Kg,
    const bf16* __restrict__ Vtg, const float* __restrict__ biasg,
    const int* __restrict__ rmask, bf16* __restrict__ Og)
{
  const int b = blockIdx.z, h = blockIdx.y, q0 = blockIdx.x*128;
  const int tid = threadIdx.x;
  const int w = tid>>6, lane = tid&63, g = lane>>4, c = lane&15;
  const int bh = b*NHEADS + h;

  __shared__ __align__(16) bf16  k_lds[2][64*64];     // 8KB/buf, swizzled (row&7)<<4
  __shared__ __align__(16) bf16  vt_lds[2][64*64];    // row=d linear, j cols, swizzled
  __shared__ __align__(16) float bias_lds[2][8*64];   // row=t, 16B-slot XOR (t&7)

  const int qrow = q0 + w*16 + c;
  const bf16* qptr = Qg + ((size_t)bh*SEQ + qrow)*DKH;
  bf16x8v qf[2];
  qf[0] = *(const bf16x8v*)(qptr + g*8);
  qf[1] = *(const bf16x8v*)(qptr + 32 + g*8);

  const int tq = rmask[b*SEQ + qrow];                 // q-side resource class (per lane)
  const int tsw = (tq&7) << 2;                        // bias dword-XOR

  f32x4v oacc[4];
  #pragma unroll
  for (int dt=0;dt<4;dt++) oacc[dt] = {0.f,0.f,0.f,0.f};
  float mrow = -1e30f, lrow = 0.f;

  // staging: 512 chunks of 16B; wave w stages phys rows w*8..w*8+7
  const int rho = tid>>3;
  const int c8s = (tid&7) ^ (rho&7);
  const int jlog = ((rho>>4)&1)*32 + ((rho>>2)&3)*8 + ((rho>>5)&1)*4 + (rho&3);

  auto STAGE = [&](int j0, int nb){
    gload_lds16(Kg  + ((size_t)bh*SEQ + j0 + jlog)*DKH + (c8s<<3), &k_lds[nb][w*512]);
    gload_lds16(Vtg + ((size_t)bh*DKH + rho)*SEQ + j0 + (c8s<<3),  &vt_lds[nb][w*512]);
    if (w < 2){
      int chunk = w*64 + lane;                        // 0..127
      int tcls = chunk>>4, c16 = chunk&15;
      int jsw = (c16<<2) ^ ((tcls&7)<<2);             // pre-swizzled source dword
      gload_lds16(biasg + ((size_t)(bh*RTYPES + tcls))*SEQ + j0 + jsw, &bias_lds[nb][w*256]);
    }
  };

  auto COMPUTE = [&](int nb){
    const char*  kb_ = (const char*)k_lds[nb];
    const char*  vb_ = (const char*)vt_lds[nb];
    const float* bb_ = &bias_lds[nb][0];

    // S^T = K Q^T + bias (bias as MFMA C-init); s[nt][r] = S[j=(nt&1)*32+g*8+(nt>>1)*4+r][q=c]
    f32x4v s[4];
    #pragma unroll
    for (int nt=0;nt<4;nt++){
      int jb = (nt&1)*32 + g*8 + (nt>>1)*4;
      s[nt] = *(const f32x4v*)&bb_[tq*64 + (jb ^ tsw)];
      #pragma unroll
      for (int kt=0;kt<2;kt++){
        int row = nt*16 + c;
        bf16x8v kf = *(const bf16x8v*)(kb_ + row*128 + ((kt*64 + g*16) ^ ((row&7)<<4)));
        s[nt] = mfma16(kf, qf[kt], s[nt]);            // swapped: A=K, B=Q
      }
    }

    // row max: 15 in-lane + 2 cross-g shuffles
    float mx = s[0][0];
    #pragma unroll
    for (int nt=0;nt<4;nt++)
      #pragma unroll
      for (int r=0;r<4;r++) mx = fmaxf(mx, s[nt][r]);
    mx = fmaxf(mx, __shfl_xor(mx, 16));
    mx = fmaxf(mx, __shfl_xor(mx, 32));

    const bool skip = __all(mx - mrow <= 8.0f);       // defer-max (THR=8, exp2 units)
    const float mnew = skip ? mrow : fmaxf(mrow, mx);

    float sum = 0.f;
    #pragma unroll
    for (int nt=0;nt<4;nt++)
      #pragma unroll
      for (int r=0;r<4;r++){
        float p = exp2f(s[nt][r] - mnew);
        s[nt][r] = p;
        sum += p;
      }
    sum += __shfl_xor(sum, 16);
    sum += __shfl_xor(sum, 32);

    if (skip){
      lrow += sum;
    } else {
      float scl = exp2f(mrow - mnew);
      lrow = lrow*scl + sum;
      #pragma unroll
      for (int dt=0;dt<4;dt++)
        #pragma unroll
        for (int r=0;r<4;r++) oacc[dt][r] *= scl;
      mrow = mnew;
    }

    // P fragments for PV B-operand (register-local): pa[kt] = {s[kt][0..3], s[kt+2][0..3]}
    bf16x8v pa[2];
    #pragma unroll
    for (int kt=0;kt<2;kt++){
      pa[kt][0]=(bf16)s[kt][0];   pa[kt][1]=(bf16)s[kt][1];
      pa[kt][2]=(bf16)s[kt][2];   pa[kt][3]=(bf16)s[kt][3];
      pa[kt][4]=(bf16)s[kt+2][0]; pa[kt][5]=(bf16)s[kt+2][1];
      pa[kt][6]=(bf16)s[kt+2][2]; pa[kt][7]=(bf16)s[kt+2][3];
    }

    // O^T += V^T P : A=V^T (row=d), B=P (col=q=c); out row = d, col = q
    #pragma unroll
    for (int dt=0;dt<4;dt++){
      #pragma unroll
      for (int kt=0;kt<2;kt++){
        int vr = dt*16 + c;
        bf16x8v vf = *(const bf16x8v*)(vb_ + vr*128 + ((kt*64 + g*16) ^ ((vr&7)<<4)));
        oacc[dt] = mfma16(vf, pa[kt], oacc[dt]);
      }
    }
  };

  STAGE(0, 0);
  __syncthreads();
  int cur = 0;
  for (int t=0; t<SEQ/64; ++t){
    if (t+1 < SEQ/64) STAGE((t+1)*64, cur^1);
    COMPUTE(cur);
    __syncthreads();
    cur ^= 1;
  }

  // normalize + store: lane holds O^T[d=dt*16+g*4+r][q=c] -> b64 stores
  const float inv = 1.0f / lrow;
  #pragma unroll
  for (int dt=0;dt<4;dt++){
    bf16x4v ov;
    #pragma unroll
    for (int r=0;r<4;r++) ov[r] = (bf16)(oacc[dt][r] * inv);
    int row = q0 + w*16 + c;
    int col = h*DKH + dt*16 + g*4;
    *(bf16x4v*)&Og[(size_t)(b*SEQ + row)*D_MODEL + col] = ov;
  }
}

// ---------------- launch ----------------
extern "C" void kernel_launch(void* const* d_in, const int* in_sizes, int n_in,
                              void* d_out, int out_size, void* d_ws, size_t ws_size,
                              hipStream_t stream)
{
  (void)in_sizes; (void)n_in; (void)out_size; (void)ws_size;
  const float* x     = (const float*)d_in[0];
  const float* Wq    = (const float*)d_in[1];
  const float* bq    = (const float*)d_in[2];
  const float* Wk    = (const float*)d_in[3];
  const float* bk    = (const float*)d_in[4];
  const float* Wv    = (const float*)d_in[5];
  const float* bv    = (const float*)d_in[6];
  const float* Wo    = (const float*)d_in[7];
  const float* bo    = (const float*)d_in[8];
  const float* rbias = (const float*)d_in[9];
  const int*   rmask = (const int*)d_in[10];
  const int*   amask = (const int*)d_in[11];
  float* out = (float*)d_out;

  char* ws = (char*)d_ws;
  bf16*  xb    = (bf16*)(ws);                 //  8 MB
  bf16*  wqb   = (bf16*)(ws + (8u<<20));      //  2 MB each
  bf16*  wkb   = (bf16*)(ws + (10u<<20));
  bf16*  wvb   = (bf16*)(ws + (12u<<20));
  bf16*  wob   = (bf16*)(ws + (14u<<20));
  bf16*  qb    = (bf16*)(ws + (16u<<20));     //  8 MB Q [b][h][s][dk] (pre-scaled, exp2 domain)
  bf16*  kb    = (bf16*)(ws + (24u<<20));     //  8 MB K [b][h][s][dk]
  bf16*  vtb   = (bf16*)(ws + (32u<<20));     //  8 MB V^T [b][h][dk][s]
  bf16*  aob   = (bf16*)(ws + (40u<<20));     //  8 MB attn out [s][e]
  float* biasg = (float*)(ws + (48u<<20));    //  2 MB bias [b][h][8][S]

  convert_kernel<<<dim3(4096,6), 256, 0, stream>>>(x,Wq,Wk,Wv,Wo, xb,wqb,wkb,wvb,wob,
                                                   rbias, rmask, amask, biasg);

  GemmOuts qkv;
  qkv.W[0]=wqb; qkv.W[1]=wkb; qkv.W[2]=wvb;
  qkv.bia[0]=bq; qkv.bia[1]=bk; qkv.bia[2]=bv;
  qkv.out[0]=qb; qkv.out[1]=kb; qkv.out[2]=vtb;
  gemm_bt_kernel<1><<<dim3(D_MODEL/128, MROWS/128, 3), 256, 0, stream>>>(xb, qkv, 0.125f*LOG2E);

  attn3_kernel<<<dim3(SEQ/128, NHEADS, NBATCH), 512, 0, stream>>>(qb, kb, vtb, biasg, rmask, aob);

  GemmOuts og;
  og.W[0]=wob; og.W[1]=wob; og.W[2]=wob;
  og.bia[0]=bo; og.bia[1]=bo; og.bia[2]=bo;
  og.out[0]=out; og.out[1]=out; og.out[2]=out;
  gemm_bt_kernel<0><<<dim3(D_MODEL/128, MROWS/128), 256, 0, stream>>>(aob, og, 1.0f);
}

// Round 5
// 138.910 us; speedup vs baseline: 1.7919x; 1.0241x over previous
//
#include <hip/hip_runtime.h>
#include <cstdint>

// ---------------- problem constants ----------------
#define D_MODEL 1024
#define NHEADS  16
#define DKH     64
#define SEQ     2048
#define NBATCH  2
#define MROWS   (NBATCH*SEQ)   // 4096
#define RTYPES  8
#define LOG2E   1.44269504f

typedef __bf16 bf16;
typedef __bf16 bf16x4v __attribute__((ext_vector_type(4)));
typedef __bf16 bf16x8v __attribute__((ext_vector_type(8)));
typedef float  f32x4v  __attribute__((ext_vector_type(4)));

typedef unsigned int __attribute__((address_space(1))) as1_u32;
typedef unsigned int __attribute__((address_space(3))) as3_u32;

static __device__ __forceinline__ void gload_lds16(const void* g, void* l) {
  __builtin_amdgcn_global_load_lds((const as1_u32*)(uintptr_t)g,
                                   (as3_u32*)(uintptr_t)l, 16, 0, 0);
}

static __device__ __forceinline__ f32x4v mfma16(bf16x8v a, bf16x8v b, f32x4v c) {
  return __builtin_amdgcn_mfma_f32_16x16x32_bf16(a, b, c, 0, 0, 0);
}

// ---------------- fp32->bf16 conversion + bias precompute (flat 1D grid) --------
// chunks (float4): x 1048576 | wq/wk/wv/wo 262144 each | bias 262144 (x2 batches)
// total 2359296 chunks -> 9216 blocks x 256
__global__ void convert_kernel(const float* __restrict__ x,  const float* __restrict__ wq,
                               const float* __restrict__ wk, const float* __restrict__ wv,
                               const float* __restrict__ wo,
                               bf16* __restrict__ xb,  bf16* __restrict__ wqb,
                               bf16* __restrict__ wkb, bf16* __restrict__ wvb,
                               bf16* __restrict__ wob,
                               const float* __restrict__ rbias,
                               const int* __restrict__ rmask,
                               const int* __restrict__ amask,
                               float* __restrict__ biasg)
{
  int idx = blockIdx.x*256 + threadIdx.x;
  if (idx < 1048576){
    float4 v = ((const float4*)x)[idx];
    bf16x4v o = { (bf16)v.x, (bf16)v.y, (bf16)v.z, (bf16)v.w };
    ((bf16x4v*)xb)[idx] = o;
  } else if (idx < 2097152){
    int r = (idx - 1048576) >> 18;          // 0..3
    int i = (idx - 1048576) & 262143;
    const float* src; bf16* dst;
    if (r == 0)      { src = wq; dst = wqb; }
    else if (r == 1) { src = wk; dst = wkb; }
    else if (r == 2) { src = wv; dst = wvb; }
    else             { src = wo; dst = wob; }
    float4 v = ((const float4*)src)[i];
    bf16x4v o = { (bf16)v.x, (bf16)v.y, (bf16)v.z, (bf16)v.w };
    ((bf16x4v*)dst)[i] = o;
  } else {
    int i = idx - 2097152;                  // 0..262143
    #pragma unroll
    for (int bb=0; bb<NBATCH; bb++){
      int id2 = bb*(NHEADS*RTYPES*SEQ) + i;
      int j  = id2 & (SEQ-1);
      int t  = (id2 >> 11) & 7;
      int hh = (id2 >> 14) & 15;
      int rj = rmask[bb*SEQ + j];
      float am = amask[bb*SEQ + j] ? 0.f : -1e9f;
      biasg[id2] = (rbias[(hh*RTYPES + t)*RTYPES + rj] + am) * LOG2E;
    }
  }
}

// ---------------- NT GEMM, 2-phase double-buffered ----------------
// FUSED=1: grid (8,32,3); z=0 -> Q [b][h][s][dk] (scale), z=1 -> K same, z=2 -> V^T
// FUSED=0: grid (8,32); f32 out [m][n]
struct GemmOuts { const bf16* W[3]; const float* bia[3]; void* out[3]; };

template<int FUSED>
__global__ __launch_bounds__(256, 3) void gemm_bt_kernel(
    const bf16* __restrict__ A, GemmOuts args, float qscale)
{
  const int K  = D_MODEL;
  const int z  = FUSED ? blockIdx.z : 0;
  const bf16*  Bw   = args.W[z];
  const float* bias = args.bia[z];
  void* outp        = args.out[z];
  const float scale = (FUSED && z==0) ? qscale : 1.0f;

  const int n0 = blockIdx.x*128, m0 = blockIdx.y*128;
  const int tid = threadIdx.x;
  const int w = tid>>6, lane = tid&63, g = lane>>4, c = lane&15;
  const int wm = w>>1, wn = w&1;

  __shared__ __align__(16) bf16 a_lds[2][128*32];
  __shared__ __align__(16) bf16 b_lds[2][128*32];

  const f32x4v fzero = {0.f,0.f,0.f,0.f};
  f32x4v acc[4][4];
  for (int i=0;i<4;i++) for (int j=0;j<4;j++) acc[i][j] = fzero;

  const int srow = tid>>2, sc8 = tid&3;

  auto STAGE = [&](int k0, int nb){
    gload_lds16(A  + (size_t)(m0+srow)*K     + k0 + sc8*8, &a_lds[nb][(w*64)*8]);
    gload_lds16(Bw + (size_t)(n0+srow)*K     + k0 + sc8*8, &b_lds[nb][(w*64)*8]);
    gload_lds16(A  + (size_t)(m0+64+srow)*K  + k0 + sc8*8, &a_lds[nb][(256 + w*64)*8]);
    gload_lds16(Bw + (size_t)(n0+64+srow)*K  + k0 + sc8*8, &b_lds[nb][(256 + w*64)*8]);
  };

  auto COMPUTE = [&](int nb){
    bf16x8v af[4], bfv[4];
    #pragma unroll
    for (int mt=0;mt<4;mt++)
      af[mt] = *(const bf16x8v*)&a_lds[nb][(wm*64 + mt*16 + c)*32 + g*8];
    #pragma unroll
    for (int nt=0;nt<4;nt++)
      bfv[nt] = *(const bf16x8v*)&b_lds[nb][(wn*64 + nt*16 + c)*32 + g*8];
    #pragma unroll
    for (int mt=0;mt<4;mt++)
      #pragma unroll
      for (int nt=0;nt<4;nt++)
        acc[mt][nt] = mfma16(af[mt], bfv[nt], acc[mt][nt]);
  };

  STAGE(0, 0);
  __syncthreads();
  int cur = 0;
  for (int k0=32; k0<K; k0+=32){
    STAGE(k0, cur^1);
    COMPUTE(cur);
    __syncthreads();
    cur ^= 1;
  }
  COMPUTE(cur);

  #pragma unroll
  for (int mt=0;mt<4;mt++){
    #pragma unroll
    for (int nt=0;nt<4;nt++){
      if (FUSED && z == 2){
        int m = m0 + wm*64 + mt*16 + g*4;
        int n = n0 + wn*64 + nt*16 + c;
        int bb=m>>11, s=m&2047, hh=n>>6, dk=n&63;
        float bn = bias[n];
        bf16x4v ov;
        #pragma unroll
        for (int r=0;r<4;r++) ov[r] = (bf16)(acc[mt][nt][r] + bn);
        *(bf16x4v*)&((bf16*)outp)[(((size_t)bb*NHEADS+hh)*DKH + dk)*SEQ + s] = ov;
      } else {
        #pragma unroll
        for (int r=0;r<4;r++){
          int m = m0 + wm*64 + mt*16 + g*4 + r;
          int n = n0 + wn*64 + nt*16 + c;
          float v = acc[mt][nt][r] + bias[n];
          if (FUSED){
            v *= scale;
            int bb=m>>11, s=m&2047, hh=n>>6, dk=n&63;
            ((bf16*)outp)[(((size_t)bb*NHEADS+hh)*SEQ + s)*DKH + dk] = (bf16)v;
          } else {
            ((float*)outp)[(size_t)m*D_MODEL + n] = v;
          }
        }
      }
    }
  }
}

// ---------------- flash attention v4 ----------------
// As v3 (swapped QK^T, in-register softmax, register-local P->PV), plus:
//  - row-sum via MFMA with ones A-operand (lacc) -> kills 16 v_add + 2 shfl/tile
//  - max3-tree row max (15 -> 8 VALU)
//  - 3-buffer pipeline, raw s_barrier + counted s_waitcnt vmcnt(N) (T3/T4):
//    next-tile global_load_lds stay in flight across the barrier.
__global__ __launch_bounds__(512, 4) void attn4_kernel(
    const bf16* __restrict__ Qg, const bf16* __restrict__ Kg,
    const bf16* __restrict__ Vtg, const float* __restrict__ biasg,
    const int* __restrict__ rmask, bf16* __restrict__ Og)
{
  const int b = blockIdx.z, h = blockIdx.y, q0 = blockIdx.x*128;
  const int tid = threadIdx.x;
  const int w = tid>>6, lane = tid&63, g = lane>>4, c = lane&15;
  const int bh = b*NHEADS + h;
  const int NT = SEQ/64;                              // 32 tiles

  __shared__ __align__(16) bf16  k_lds[3][64*64];     // 8KB/buf, swizzled (row&7)<<4
  __shared__ __align__(16) bf16  vt_lds[3][64*64];    // row=d linear, j cols, swizzled
  __shared__ __align__(16) float bias_lds[3][8*64];   // row=t, 16B-slot XOR (t&7)

  const int qrow = q0 + w*16 + c;
  const bf16* qptr = Qg + ((size_t)bh*SEQ + qrow)*DKH;
  bf16x8v qf[2];
  qf[0] = *(const bf16x8v*)(qptr + g*8);
  qf[1] = *(const bf16x8v*)(qptr + 32 + g*8);

  const int tq = rmask[b*SEQ + qrow];                 // q-side resource class
  const int tsw = (tq&7) << 2;

  bf16x8v ones;
  #pragma unroll
  for (int i=0;i<8;i++) ones[i] = (bf16)1.0f;

  f32x4v oacc[4];
  #pragma unroll
  for (int dt=0;dt<4;dt++) oacc[dt] = {0.f,0.f,0.f,0.f};
  f32x4v lacc = {0.f,0.f,0.f,0.f};                    // row-sum accumulator (all 4 equal)
  float mrow = -1e30f;

  // staging lane constants
  const int rho = tid>>3;
  const int c8s = (tid&7) ^ (rho&7);
  const int jlog = ((rho>>4)&1)*32 + ((rho>>2)&3)*8 + ((rho>>5)&1)*4 + (rho&3);

  auto STAGE = [&](int j0, int nb){
    gload_lds16(Kg  + ((size_t)bh*SEQ + j0 + jlog)*DKH + (c8s<<3), &k_lds[nb][w*512]);
    gload_lds16(Vtg + ((size_t)bh*DKH + rho)*SEQ + j0 + (c8s<<3),  &vt_lds[nb][w*512]);
    if (w < 2){
      int chunk = w*64 + lane;
      int tcls = chunk>>4, c16 = chunk&15;
      int jsw = (c16<<2) ^ ((tcls&7)<<2);
      gload_lds16(biasg + ((size_t)(bh*RTYPES + tcls))*SEQ + j0 + jsw, &bias_lds[nb][w*256]);
    }
  };

  auto COMPUTE = [&](int nb){
    const char*  kb_ = (const char*)k_lds[nb];
    const char*  vb_ = (const char*)vt_lds[nb];
    const float* bb_ = &bias_lds[nb][0];

    // S^T = K Q^T + bias-C-init; s[nt][r] = S[j=(nt&1)*32+g*8+(nt>>1)*4+r][q=c]
    f32x4v s[4];
    #pragma unroll
    for (int nt=0;nt<4;nt++){
      int jb = (nt&1)*32 + g*8 + (nt>>1)*4;
      s[nt] = *(const f32x4v*)&bb_[tq*64 + (jb ^ tsw)];
      #pragma unroll
      for (int kt=0;kt<2;kt++){
        int row = nt*16 + c;
        bf16x8v kf = *(const bf16x8v*)(kb_ + row*128 + ((kt*64 + g*16) ^ ((row&7)<<4)));
        s[nt] = mfma16(kf, qf[kt], s[nt]);            // swapped: A=K, B=Q
      }
    }

    // row max: max3 tree (8 ops) + 2 cross-group shuffles
    float a0 = fmaxf(fmaxf(s[0][0],s[0][1]),s[0][2]);
    float a1 = fmaxf(fmaxf(s[0][3],s[1][0]),s[1][1]);
    float a2 = fmaxf(fmaxf(s[1][2],s[1][3]),s[2][0]);
    float a3 = fmaxf(fmaxf(s[2][1],s[2][2]),s[2][3]);
    float a4 = fmaxf(fmaxf(s[3][0],s[3][1]),s[3][2]);
    float mx = fmaxf(fmaxf(fmaxf(a0,a1),a2), fmaxf(fmaxf(a3,a4),s[3][3]));
    mx = fmaxf(mx, __shfl_xor(mx, 16));
    mx = fmaxf(mx, __shfl_xor(mx, 32));

    // defer-max (THR=8 exp2 units): rescale only on significant max growth
    if (!__all(mx - mrow <= 8.0f)){
      float mnew = fmaxf(mrow, mx);
      float scl = exp2f(mrow - mnew);
      #pragma unroll
      for (int dt=0;dt<4;dt++)
        #pragma unroll
        for (int r=0;r<4;r++) oacc[dt][r] *= scl;
      #pragma unroll
      for (int r=0;r<4;r++) lacc[r] *= scl;
      mrow = mnew;
    }

    #pragma unroll
    for (int nt=0;nt<4;nt++)
      #pragma unroll
      for (int r=0;r<4;r++)
        s[nt][r] = exp2f(s[nt][r] - mrow);

    // P fragments (register-local): pa[kt] = {s[kt][0..3], s[kt+2][0..3]}
    bf16x8v pa[2];
    #pragma unroll
    for (int kt=0;kt<2;kt++){
      pa[kt][0]=(bf16)s[kt][0];   pa[kt][1]=(bf16)s[kt][1];
      pa[kt][2]=(bf16)s[kt][2];   pa[kt][3]=(bf16)s[kt][3];
      pa[kt][4]=(bf16)s[kt+2][0]; pa[kt][5]=(bf16)s[kt+2][1];
      pa[kt][6]=(bf16)s[kt+2][2]; pa[kt][7]=(bf16)s[kt+2][3];
    }

    // row-sum on the MFMA pipe: lacc += ones^T P  (all 4 regs = sum_j P[j][q=c])
    lacc = mfma16(ones, pa[0], lacc);
    lacc = mfma16(ones, pa[1], lacc);

    // O^T += V^T P
    #pragma unroll
    for (int dt=0;dt<4;dt++){
      #pragma unroll
      for (int kt=0;kt<2;kt++){
        int vr = dt*16 + c;
        bf16x8v vf = *(const bf16x8v*)(vb_ + vr*128 + ((kt*64 + g*16) ^ ((vr&7)<<4)));
        oacc[dt] = mfma16(vf, pa[kt], oacc[dt]);
      }
    }
  };

  // ---- 3-buffer pipeline with counted vmcnt (T3/T4) ----
  // per-wave VMEM ops per STAGE: 3 (w<2, incl bias) or 2 (w>=2)
  STAGE(0, 0);
  STAGE(64, 1);
  if (w < 2) asm volatile("s_waitcnt vmcnt(3)" ::: "memory");
  else       asm volatile("s_waitcnt vmcnt(2)" ::: "memory");
  __builtin_amdgcn_s_barrier();

  int cur = 0;
  for (int t=0; t<NT; ++t){
    if (t+2 < NT){
      int nb2 = cur+2; if (nb2 >= 3) nb2 -= 3;
      STAGE((t+2)*64, nb2);
    }
    COMPUTE(cur);
    if (t+2 < NT){
      if (w < 2) asm volatile("s_waitcnt vmcnt(3)" ::: "memory");
      else       asm volatile("s_waitcnt vmcnt(2)" ::: "memory");
    } else {
      asm volatile("s_waitcnt vmcnt(0)" ::: "memory");
    }
    __builtin_amdgcn_s_barrier();
    cur = (cur+1 == 3) ? 0 : cur+1;
  }

  // normalize + store: lane holds O^T[d=dt*16+g*4+r][q=c]
  const float inv = 1.0f / lacc[0];
  #pragma unroll
  for (int dt=0;dt<4;dt++){
    bf16x4v ov;
    #pragma unroll
    for (int r=0;r<4;r++) ov[r] = (bf16)(oacc[dt][r] * inv);
    int row = q0 + w*16 + c;
    int col = h*DKH + dt*16 + g*4;
    *(bf16x4v*)&Og[(size_t)(b*SEQ + row)*D_MODEL + col] = ov;
  }
}

// ---------------- launch ----------------
extern "C" void kernel_launch(void* const* d_in, const int* in_sizes, int n_in,
                              void* d_out, int out_size, void* d_ws, size_t ws_size,
                              hipStream_t stream)
{
  (void)in_sizes; (void)n_in; (void)out_size; (void)ws_size;
  const float* x     = (const float*)d_in[0];
  const float* Wq    = (const float*)d_in[1];
  const float* bq    = (const float*)d_in[2];
  const float* Wk    = (const float*)d_in[3];
  const float* bk    = (const float*)d_in[4];
  const float* Wv    = (const float*)d_in[5];
  const float* bv    = (const float*)d_in[6];
  const float* Wo    = (const float*)d_in[7];
  const float* bo    = (const float*)d_in[8];
  const float* rbias = (const float*)d_in[9];
  const int*   rmask = (const int*)d_in[10];
  const int*   amask = (const int*)d_in[11];
  float* out = (float*)d_out;

  char* ws = (char*)d_ws;
  bf16*  xb    = (bf16*)(ws);                 //  8 MB
  bf16*  wqb   = (bf16*)(ws + (8u<<20));      //  2 MB each
  bf16*  wkb   = (bf16*)(ws + (10u<<20));
  bf16*  wvb   = (bf16*)(ws + (12u<<20));
  bf16*  wob   = (bf16*)(ws + (14u<<20));
  bf16*  qb    = (bf16*)(ws + (16u<<20));     //  8 MB Q (pre-scaled, exp2 domain)
  bf16*  kb    = (bf16*)(ws + (24u<<20));     //  8 MB K
  bf16*  vtb   = (bf16*)(ws + (32u<<20));     //  8 MB V^T
  bf16*  aob   = (bf16*)(ws + (40u<<20));     //  8 MB attn out [s][e]
  float* biasg = (float*)(ws + (48u<<20));    //  2 MB bias [b][h][8][S]

  convert_kernel<<<9216, 256, 0, stream>>>(x,Wq,Wk,Wv,Wo, xb,wqb,wkb,wvb,wob,
                                           rbias, rmask, amask, biasg);

  GemmOuts qkv;
  qkv.W[0]=wqb; qkv.W[1]=wkb; qkv.W[2]=wvb;
  qkv.bia[0]=bq; qkv.bia[1]=bk; qkv.bia[2]=bv;
  qkv.out[0]=qb; qkv.out[1]=kb; qkv.out[2]=vtb;
  gemm_bt_kernel<1><<<dim3(D_MODEL/128, MROWS/128, 3), 256, 0, stream>>>(xb, qkv, 0.125f*LOG2E);

  attn4_kernel<<<dim3(SEQ/128, NHEADS, NBATCH), 512, 0, stream>>>(qb, kb, vtb, biasg, rmask, aob);

  GemmOuts og;
  og.W[0]=wob; og.W[1]=wob; og.W[2]=wob;
  og.bia[0]=bo; og.bia[1]=bo; og.bia[2]=bo;
  og.out[0]=out; og.out[1]=out; og.out[2]=out;
  gemm_bt_kernel<0><<<dim3(D_MODEL/128, MROWS/128), 256, 0, stream>>>(aob, og, 1.0f);
}

// Round 6
// 136.916 us; speedup vs baseline: 1.8180x; 1.0146x over previous
//
#include <hip/hip_runtime.h>
#include <cstdint>

// ---------------- problem constants ----------------
#define D_MODEL 1024
#define NHEADS  16
#define DKH     64
#define SEQ     2048
#define NBATCH  2
#define MROWS   (NBATCH*SEQ)   // 4096
#define RTYPES  8
#define LOG2E   1.44269504f

typedef __bf16 bf16;
typedef __bf16 bf16x4v __attribute__((ext_vector_type(4)));
typedef __bf16 bf16x8v __attribute__((ext_vector_type(8)));
typedef float  f32x4v  __attribute__((ext_vector_type(4)));
typedef float  f32x8v  __attribute__((ext_vector_type(8)));
typedef float  f32x16v __attribute__((ext_vector_type(16)));

typedef unsigned int __attribute__((address_space(1))) as1_u32;
typedef unsigned int __attribute__((address_space(3))) as3_u32;

static __device__ __forceinline__ void gload_lds16(const void* g, void* l) {
  __builtin_amdgcn_global_load_lds((const as1_u32*)(uintptr_t)g,
                                   (as3_u32*)(uintptr_t)l, 16, 0, 0);
}

static __device__ __forceinline__ f32x4v mfma16(bf16x8v a, bf16x8v b, f32x4v c) {
  return __builtin_amdgcn_mfma_f32_16x16x32_bf16(a, b, c, 0, 0, 0);
}
static __device__ __forceinline__ f32x16v mfma32(bf16x8v a, bf16x8v b, f32x16v c) {
  return __builtin_amdgcn_mfma_f32_32x32x16_bf16(a, b, c, 0, 0, 0);
}

// ---------------- fp32->bf16 conversion + bias precompute (flat 1D grid) --------
__global__ void convert_kernel(const float* __restrict__ x,  const float* __restrict__ wq,
                               const float* __restrict__ wk, const float* __restrict__ wv,
                               const float* __restrict__ wo,
                               bf16* __restrict__ xb,  bf16* __restrict__ wqb,
                               bf16* __restrict__ wkb, bf16* __restrict__ wvb,
                               bf16* __restrict__ wob,
                               const float* __restrict__ rbias,
                               const int* __restrict__ rmask,
                               const int* __restrict__ amask,
                               float* __restrict__ biasg)
{
  int idx = blockIdx.x*256 + threadIdx.x;
  if (idx < 1048576){
    float4 v = ((const float4*)x)[idx];
    bf16x4v o = { (bf16)v.x, (bf16)v.y, (bf16)v.z, (bf16)v.w };
    ((bf16x4v*)xb)[idx] = o;
  } else if (idx < 2097152){
    int r = (idx - 1048576) >> 18;
    int i = (idx - 1048576) & 262143;
    const float* src; bf16* dst;
    if (r == 0)      { src = wq; dst = wqb; }
    else if (r == 1) { src = wk; dst = wkb; }
    else if (r == 2) { src = wv; dst = wvb; }
    else             { src = wo; dst = wob; }
    float4 v = ((const float4*)src)[i];
    bf16x4v o = { (bf16)v.x, (bf16)v.y, (bf16)v.z, (bf16)v.w };
    ((bf16x4v*)dst)[i] = o;
  } else {
    int i = idx - 2097152;
    #pragma unroll
    for (int bb=0; bb<NBATCH; bb++){
      int id2 = bb*(NHEADS*RTYPES*SEQ) + i;
      int j  = id2 & (SEQ-1);
      int t  = (id2 >> 11) & 7;
      int hh = (id2 >> 14) & 15;
      int rj = rmask[bb*SEQ + j];
      float am = amask[bb*SEQ + j] ? 0.f : -1e9f;
      biasg[id2] = (rbias[(hh*RTYPES + t)*RTYPES + rj] + am) * LOG2E;
    }
  }
}

// ---------------- NT GEMM, 2-phase double-buffered (unchanged) ----------------
struct GemmOuts { const bf16* W[3]; const float* bia[3]; void* out[3]; };

template<int FUSED>
__global__ __launch_bounds__(256, 3) void gemm_bt_kernel(
    const bf16* __restrict__ A, GemmOuts args, float qscale)
{
  const int K  = D_MODEL;
  const int z  = FUSED ? blockIdx.z : 0;
  const bf16*  Bw   = args.W[z];
  const float* bias = args.bia[z];
  void* outp        = args.out[z];
  const float scale = (FUSED && z==0) ? qscale : 1.0f;

  const int n0 = blockIdx.x*128, m0 = blockIdx.y*128;
  const int tid = threadIdx.x;
  const int w = tid>>6, lane = tid&63, g = lane>>4, c = lane&15;
  const int wm = w>>1, wn = w&1;

  __shared__ __align__(16) bf16 a_lds[2][128*32];
  __shared__ __align__(16) bf16 b_lds[2][128*32];

  const f32x4v fzero = {0.f,0.f,0.f,0.f};
  f32x4v acc[4][4];
  for (int i=0;i<4;i++) for (int j=0;j<4;j++) acc[i][j] = fzero;

  const int srow = tid>>2, sc8 = tid&3;

  auto STAGE = [&](int k0, int nb){
    gload_lds16(A  + (size_t)(m0+srow)*K     + k0 + sc8*8, &a_lds[nb][(w*64)*8]);
    gload_lds16(Bw + (size_t)(n0+srow)*K     + k0 + sc8*8, &b_lds[nb][(w*64)*8]);
    gload_lds16(A  + (size_t)(m0+64+srow)*K  + k0 + sc8*8, &a_lds[nb][(256 + w*64)*8]);
    gload_lds16(Bw + (size_t)(n0+64+srow)*K  + k0 + sc8*8, &b_lds[nb][(256 + w*64)*8]);
  };

  auto COMPUTE = [&](int nb){
    bf16x8v af[4], bfv[4];
    #pragma unroll
    for (int mt=0;mt<4;mt++)
      af[mt] = *(const bf16x8v*)&a_lds[nb][(wm*64 + mt*16 + c)*32 + g*8];
    #pragma unroll
    for (int nt=0;nt<4;nt++)
      bfv[nt] = *(const bf16x8v*)&b_lds[nb][(wn*64 + nt*16 + c)*32 + g*8];
    #pragma unroll
    for (int mt=0;mt<4;mt++)
      #pragma unroll
      for (int nt=0;nt<4;nt++)
        acc[mt][nt] = mfma16(af[mt], bfv[nt], acc[mt][nt]);
  };

  STAGE(0, 0);
  __syncthreads();
  int cur = 0;
  for (int k0=32; k0<K; k0+=32){
    STAGE(k0, cur^1);
    COMPUTE(cur);
    __syncthreads();
    cur ^= 1;
  }
  COMPUTE(cur);

  #pragma unroll
  for (int mt=0;mt<4;mt++){
    #pragma unroll
    for (int nt=0;nt<4;nt++){
      if (FUSED && z == 2){
        int m = m0 + wm*64 + mt*16 + g*4;
        int n = n0 + wn*64 + nt*16 + c;
        int bb=m>>11, s=m&2047, hh=n>>6, dk=n&63;
        float bn = bias[n];
        bf16x4v ov;
        #pragma unroll
        for (int r=0;r<4;r++) ov[r] = (bf16)(acc[mt][nt][r] + bn);
        *(bf16x4v*)&((bf16*)outp)[(((size_t)bb*NHEADS+hh)*DKH + dk)*SEQ + s] = ov;
      } else {
        #pragma unroll
        for (int r=0;r<4;r++){
          int m = m0 + wm*64 + mt*16 + g*4 + r;
          int n = n0 + wn*64 + nt*16 + c;
          float v = acc[mt][nt][r] + bias[n];
          if (FUSED){
            v *= scale;
            int bb=m>>11, s=m&2047, hh=n>>6, dk=n&63;
            ((bf16*)outp)[(((size_t)bb*NHEADS+hh)*SEQ + s)*DKH + dk] = (bf16)v;
          } else {
            ((float*)outp)[(size_t)m*D_MODEL + n] = v;
          }
        }
      }
    }
  }
}

// ---------------- flash attention v5: 32x32 MFMA, 32 q-rows/wave ----------------
// grid (SEQ/128, NHEADS, NBATCH) x 256 (4 waves x 32 q-rows). 2 blocks/CU.
// Swapped S^T = mfma32(A=K, B=Q): lane (q5=lane&31, hi=lane>>5) owns q-row q5,
// 32 j-values in C regs (j-set {j:(j>>3)&1==hi}). K tile rows sigma-permuted
// (bit2<->bit3 within each 32-row half) so PV B-fragments are pure register
// renames of the S regs: pa[m] = s[m>>1][e + (m&1)*8]. PV: O^T = mfma32(V^T, P).
// Row-sum on MFMA pipe (ones-A). Bias as MFMA C-init from tq-XOR-swizzled LDS.
// 3-buffer pipeline, counted vmcnt (loads stay in flight across barriers).
__global__ __launch_bounds__(256, 2) void attn5_kernel(
    const bf16* __restrict__ Qg, const bf16* __restrict__ Kg,
    const bf16* __restrict__ Vtg, const float* __restrict__ biasg,
    const int* __restrict__ rmask, bf16* __restrict__ Og)
{
  const int b = blockIdx.z, h = blockIdx.y, q0 = blockIdx.x*128;
  const int tid = threadIdx.x;
  const int w = tid>>6, lane = tid&63;
  const int q5 = lane&31, hi = lane>>5;
  const int bh = b*NHEADS + h;
  const int NT = SEQ/64;

  __shared__ __align__(16) bf16  k_lds[3][64*64];    // 8KB/buf; byte ^= (row&7)<<4
  __shared__ __align__(16) bf16  vt_lds[3][64*64];   // row=d, same swizzle
  __shared__ __align__(16) float bias_lds[3][8*64];  // word[t*64+W] = bias[t][W^(t*8)]

  // Q fragments (B-operand): col=q5, k=hi*8+e; frag kc covers d = kc*16+hi*8+0..7
  const int qrow = q0 + w*32 + q5;
  const bf16* qptr = Qg + ((size_t)bh*SEQ + qrow)*DKH;
  bf16x8v qf[4];
  #pragma unroll
  for (int kc=0;kc<4;kc++)
    qf[kc] = *(const bf16x8v*)(qptr + kc*16 + hi*8);

  const int tq = rmask[b*SEQ + qrow];

  // bias C-init word offsets (constant across tiles): per nt, 4 b128 reads
  int boff[2][4];
  #pragma unroll
  for (int nt=0;nt<2;nt++){
    const int j00 = nt*32 + hi*8;
    boff[nt][0] = tq*64 + ((j00 +  0) ^ (tq*8));
    boff[nt][1] = tq*64 + ((j00 +  4) ^ (tq*8));
    boff[nt][2] = tq*64 + ((j00 + 16) ^ (tq*8));
    boff[nt][3] = tq*64 + ((j00 + 20) ^ (tq*8));
  }

  bf16x8v ones;
  #pragma unroll
  for (int i=0;i<8;i++) ones[i] = (bf16)1.0f;

  f32x16v oacc[2];
  #pragma unroll
  for (int dt=0;dt<2;dt++)
    #pragma unroll
    for (int r=0;r<16;r++) oacc[dt][r] = 0.f;
  f32x16v lacc;
  #pragma unroll
  for (int r=0;r<16;r++) lacc[r] = 0.f;
  float mrow = -1e30f;

  // staging: K/V 512 chunks of 16B each (2 per thread); bias 128 chunks (waves 0,1)
  // phys row p holds logical j = sigma(p) (bit2<->bit3 swap within 32-row half)
  auto STAGE = [&](int j0, int nb){
    #pragma unroll
    for (int i=0;i<2;i++){
      const int chunk = i*256 + tid;
      const int p = chunk>>3, c8 = chunk&7;
      const int jsrc = (p & 32) + (p & 3) + (((p>>3)&1)<<2) + (((p>>2)&1)<<3) + (p & 16);
      const int dsrc = (c8 ^ (p&7)) << 3;
      gload_lds16(Kg  + ((size_t)bh*SEQ + j0 + jsrc)*DKH + dsrc, &k_lds[nb][(i*256 + w*64)*8]);
      gload_lds16(Vtg + ((size_t)bh*DKH + p)*SEQ + j0 + dsrc,    &vt_lds[nb][(i*256 + w*64)*8]);
    }
    if (w < 2){
      const int chunk = w*64 + lane;
      const int t = chunk>>4, c16 = chunk&15;
      const int jsw = (c16<<2) ^ (t<<3);
      gload_lds16(biasg + ((size_t)(bh*RTYPES + t))*SEQ + j0 + jsw, &bias_lds[nb][w*256]);
    }
  };

  auto COMPUTE = [&](int nb){
    const char*  kb_ = (const char*)k_lds[nb];
    const char*  vb_ = (const char*)vt_lds[nb];
    const float* bb_ = &bias_lds[nb][0];

    // S^T = K Q^T + bias-C-init; s[nt] reg r: j = nt*32 + (r&3) + ((r>>2)&1)*4 + hi*8 + (r>>3)*16
    f32x16v s[2];
    #pragma unroll
    for (int nt=0;nt<2;nt++){
      f32x4v b0 = *(const f32x4v*)&bb_[boff[nt][0]];
      f32x4v b1 = *(const f32x4v*)&bb_[boff[nt][1]];
      f32x4v b2 = *(const f32x4v*)&bb_[boff[nt][2]];
      f32x4v b3 = *(const f32x4v*)&bb_[boff[nt][3]];
      f32x8v h0 = __builtin_shufflevector(b0, b1, 0,1,2,3,4,5,6,7);
      f32x8v h1 = __builtin_shufflevector(b2, b3, 0,1,2,3,4,5,6,7);
      s[nt] = __builtin_shufflevector(h0, h1, 0,1,2,3,4,5,6,7,8,9,10,11,12,13,14,15);
      #pragma unroll
      for (int kc=0;kc<4;kc++){
        const int row = nt*32 + q5;
        bf16x8v kf = *(const bf16x8v*)(kb_ + row*128 + ((kc*32 + hi*16) ^ ((row&7)<<4)));
        s[nt] = mfma32(kf, qf[kc], s[nt]);      // swapped: A=K, B=Q
      }
    }

    // row max over lane's 32 + hi-partner
    float mx = s[0][0];
    #pragma unroll
    for (int r=1;r<16;r++) mx = fmaxf(mx, s[0][r]);
    #pragma unroll
    for (int r=0;r<16;r++) mx = fmaxf(mx, s[1][r]);
    mx = fmaxf(mx, __shfl_xor(mx, 32));

    // defer-max (THR=8, exp2 units)
    if (!__all(mx - mrow <= 8.0f)){
      float mnew = fmaxf(mrow, mx);
      float scl = exp2f(mrow - mnew);
      #pragma unroll
      for (int dt=0;dt<2;dt++)
        #pragma unroll
        for (int r=0;r<16;r++) oacc[dt][r] *= scl;
      #pragma unroll
      for (int r=0;r<16;r++) lacc[r] *= scl;
      mrow = mnew;
    }

    #pragma unroll
    for (int nt=0;nt<2;nt++)
      #pragma unroll
      for (int r=0;r<16;r++)
        s[nt][r] = exp2f(s[nt][r] - mrow);

    // P fragments: pure register rename (sigma makes this exact)
    bf16x8v pa[4];
    #pragma unroll
    for (int m=0;m<4;m++)
      #pragma unroll
      for (int e=0;e<8;e++)
        pa[m][e] = (bf16)s[m>>1][e + (m&1)*8];

    // row-sum on MFMA pipe: lacc rows all = sum_j P[j][q]
    #pragma unroll
    for (int m=0;m<4;m++) lacc = mfma32(ones, pa[m], lacc);

    // O^T += V^T P : A-frag row=d (dt*32+q5), k = j = m*16+hi*8+e
    #pragma unroll
    for (int dt=0;dt<2;dt++){
      #pragma unroll
      for (int m=0;m<4;m++){
        const int row = dt*32 + q5;
        bf16x8v vf = *(const bf16x8v*)(vb_ + row*128 + ((m*32 + hi*16) ^ ((row&7)<<4)));
        oacc[dt] = mfma32(vf, pa[m], oacc[dt]);
      }
    }
  };

  // ---- 3-buffer pipeline with counted vmcnt ----
  // per-thread VMEM ops per STAGE: 5 (w<2) or 4
  STAGE(0, 0);
  STAGE(64, 1);
  if (w < 2) asm volatile("s_waitcnt vmcnt(5)" ::: "memory");
  else       asm volatile("s_waitcnt vmcnt(4)" ::: "memory");
  __builtin_amdgcn_s_barrier();

  int cur = 0;
  for (int t=0; t<NT; ++t){
    if (t+2 < NT){
      int nb2 = cur+2; if (nb2 >= 3) nb2 -= 3;
      STAGE((t+2)*64, nb2);
    }
    COMPUTE(cur);
    if (t+2 < NT){
      if (w < 2) asm volatile("s_waitcnt vmcnt(5)" ::: "memory");
      else       asm volatile("s_waitcnt vmcnt(4)" ::: "memory");
    } else {
      asm volatile("s_waitcnt vmcnt(0)" ::: "memory");
    }
    __builtin_amdgcn_s_barrier();
    cur = (cur+1 == 3) ? 0 : cur+1;
  }

  // normalize + store: lane holds O^T[d = dt*32 + (r&3)+8*(r>>2)+4*hi][q=q5]
  const float inv = 1.0f / lacc[0];
  #pragma unroll
  for (int dt=0;dt<2;dt++){
    #pragma unroll
    for (int rq=0;rq<4;rq++){
      bf16x4v ov;
      #pragma unroll
      for (int k=0;k<4;k++) ov[k] = (bf16)(oacc[dt][rq*4+k] * inv);
      const int d = dt*32 + 8*rq + 4*hi;
      *(bf16x4v*)&Og[(size_t)(b*SEQ + qrow)*D_MODEL + h*DKH + d] = ov;
    }
  }
}

// ---------------- launch ----------------
extern "C" void kernel_launch(void* const* d_in, const int* in_sizes, int n_in,
                              void* d_out, int out_size, void* d_ws, size_t ws_size,
                              hipStream_t stream)
{
  (void)in_sizes; (void)n_in; (void)out_size; (void)ws_size;
  const float* x     = (const float*)d_in[0];
  const float* Wq    = (const float*)d_in[1];
  const float* bq    = (const float*)d_in[2];
  const float* Wk    = (const float*)d_in[3];
  const float* bk    = (const float*)d_in[4];
  const float* Wv    = (const float*)d_in[5];
  const float* bv    = (const float*)d_in[6];
  const float* Wo    = (const float*)d_in[7];
  const float* bo    = (const float*)d_in[8];
  const float* rbias = (const float*)d_in[9];
  const int*   rmask = (const int*)d_in[10];
  const int*   amask = (const int*)d_in[11];
  float* out = (float*)d_out;

  char* ws = (char*)d_ws;
  bf16*  xb    = (bf16*)(ws);                 //  8 MB
  bf16*  wqb   = (bf16*)(ws + (8u<<20));      //  2 MB each
  bf16*  wkb   = (bf16*)(ws + (10u<<20));
  bf16*  wvb   = (bf16*)(ws + (12u<<20));
  bf16*  wob   = (bf16*)(ws + (14u<<20));
  bf16*  qb    = (bf16*)(ws + (16u<<20));     //  8 MB Q (pre-scaled, exp2 domain)
  bf16*  kb    = (bf16*)(ws + (24u<<20));     //  8 MB K
  bf16*  vtb   = (bf16*)(ws + (32u<<20));     //  8 MB V^T
  bf16*  aob   = (bf16*)(ws + (40u<<20));     //  8 MB attn out [s][e]
  float* biasg = (float*)(ws + (48u<<20));    //  2 MB bias [b][h][8][S]

  convert_kernel<<<9216, 256, 0, stream>>>(x,Wq,Wk,Wv,Wo, xb,wqb,wkb,wvb,wob,
                                           rbias, rmask, amask, biasg);

  GemmOuts qkv;
  qkv.W[0]=wqb; qkv.W[1]=wkb; qkv.W[2]=wvb;
  qkv.bia[0]=bq; qkv.bia[1]=bk; qkv.bia[2]=bv;
  qkv.out[0]=qb; qkv.out[1]=kb; qkv.out[2]=vtb;
  gemm_bt_kernel<1><<<dim3(D_MODEL/128, MROWS/128, 3), 256, 0, stream>>>(xb, qkv, 0.125f*LOG2E);

  attn5_kernel<<<dim3(SEQ/128, NHEADS, NBATCH), 256, 0, stream>>>(qb, kb, vtb, biasg, rmask, aob);

  GemmOuts og;
  og.W[0]=wob; og.W[1]=wob; og.W[2]=wob;
  og.bia[0]=bo; og.bia[1]=bo; og.bia[2]=bo;
  og.out[0]=out; og.out[1]=out; og.out[2]=out;
  gemm_bt_kernel<0><<<dim3(D_MODEL/128, MROWS/128), 256, 0, stream>>>(aob, og, 1.0f);
}